// Round 8
// baseline (4886.895 us; speedup 1.0000x reference)
//
#include <hip/hip_runtime.h>
#include <hip/hip_bf16.h>

// LSTM_66443144069713: 3-layer biLSTM, B=256 T=512 H=192 E=128, V=20000.
// Persistent per-layer kernel: WGs 0-31 = recurrence consumers (full 512 steps,
// W_hh in VGPRs, h in LDS, gx via packed u64 agent loads PF=3); WGs 32-255 =
// GEMM producers filling an R-deep gx ring. Flag arrays, wave0-only polling.
// ROUND-8 FIX: ring depth R must be a POWER OF 2 (slot = c & (R-1)); round-7's
// R=3 aliased chunks 0/1 onto one slot -> corruption. Ladder now {R=8, R=4}.

typedef _Float16 f16;
typedef unsigned int u32;
typedef unsigned long long u64;
typedef _Float16 f16x8 __attribute__((ext_vector_type(8)));
typedef float f32x4 __attribute__((ext_vector_type(4)));

#define ATL(p) __hip_atomic_load((p), __ATOMIC_RELAXED, __HIP_MEMORY_SCOPE_AGENT)
#define ATL64(p) __hip_atomic_load((p), __ATOMIC_RELAXED, __HIP_MEMORY_SCOPE_AGENT)
#define ATS(p, v) __hip_atomic_store((p), (v), __ATOMIC_RELAXED, __HIP_MEMORY_SCOPE_AGENT)
#define ATS64(p, v) __hip_atomic_store((p), (v), __ATOMIC_RELAXED, __HIP_MEMORY_SCOPE_AGENT)

// ---------- small utility kernels ----------

__global__ void castk(const float* __restrict__ s, f16* __restrict__ d, int n) {
  int i = blockIdx.x * 256 + threadIdx.x;
  int st = gridDim.x * 256;
  for (; i < n; i += st) d[i] = (f16)s[i];
}

// W_hh (f32 [2][768][192]) -> f16 fragment layout [dir][w12][g][kk][lane][8]
__global__ void castwhh(const float* __restrict__ src, f16* __restrict__ dst) {
  int o = blockIdx.x * 256 + threadIdx.x;  // < 294912
  int e = o & 7, rest = o >> 3;
  int l = rest & 63; rest >>= 6;
  int kk = rest % 6; rest /= 6;
  int g = rest & 3; rest >>= 2;
  int w = rest % 12; int dir = rest / 12;
  int lo16 = l & 15, lhi = l >> 4;
  dst[o] = (f16)src[(size_t)(dir * 768 + g * 192 + w * 16 + lo16) * 192 + kk * 32 + lhi * 8 + e];
}

// A0[t*256+b][k] = fp16(emb[x[b][t]][k])
__global__ void embedk(const int* __restrict__ x, const float* __restrict__ emb,
                       f16* __restrict__ A0) {
  int row = blockIdx.x * 8 + (threadIdx.x >> 5);
  int t = row >> 8, b = row & 255;
  int xi = x[b * 512 + t];
  int c = (threadIdx.x & 31) * 4;
  float4 v = *(const float4*)(emb + (size_t)xi * 128 + c);
  union { f16 h[4]; uint2 u; } p;
  p.h[0] = (f16)v.x; p.h[1] = (f16)v.y; p.h[2] = (f16)v.z; p.h[3] = (f16)v.w;
  *(uint2*)(A0 + (size_t)row * 128 + c) = p.u;
}

__global__ void zerok(int* __restrict__ p) {
  p[blockIdx.x * 256 + threadIdx.x] = 0;  // 64 x 256 = 16384 ints
}

// ---------- persistent per-layer kernel ----------
// gx layout (u64 units within ring slot): seg = ((dir*TC+tl)*16 + b16)*12 + w12;
//   u64 index = seg*256 + lane*4 + g.  u64 = {lo dword: batch rows q0,q1;
//   hi dword: rows q2,q3} of gate g, f16 pairs.
// flags: done[c*nblk+blk] (0..4095), freed[4096 + c*32 + wg].
template <int KD>
__global__ __launch_bounds__(768, 3)
void persistk(const f16* __restrict__ in, const f16* __restrict__ Bt,
              const float* __restrict__ bias, u64* gxring,
              const f16* __restrict__ whh16,
              f16* __restrict__ outh, float* __restrict__ hT,
              int* flags, int Rm1, int NC, int TC, int lgTC,
              int wOut, int wHT) {
  union SMem {
    struct { uint4 A[512]; uint4 B[1536]; } g;   // 8KB + 24KB gemm staging
    f16 hb[2][16 * 200];                         // 12.8KB recurrence h
  };
  __shared__ __align__(16) SMem sm;
  int* done = flags;
  int* freed = flags + 4096;
  const int wg = blockIdx.x;
  const int tid = threadIdx.x;
  const int l = tid & 63, w = tid >> 6;
  const int lo16 = l & 15, lhi = l >> 4;
  const int TCm1 = TC - 1;
  const int lgNB = lgTC + 3;                   // nblk = 8*TC (64-row tiles x 2 dirs)
  const int nblk = 1 << lgNB;
  const size_t chunkQW = (size_t)TC * 98304;   // u64 per chunk slot

  if (wg < 32) {
    // ================= recurrence consumer =================
    const int dir = wg & 1, bblk = wg >> 1;
    const int u0 = w * 16;
    const int bb = bblk * 16 + lhi * 4;
    const int dc = dir * 192;
    const size_t segTid = (size_t)(bblk * 12 + w) * 256 + l * 4;  // u64 units
    const int dirT = dir * TC;

    f16x8 wf[4][6];
#pragma unroll
    for (int g = 0; g < 4; ++g)
#pragma unroll
      for (int kk = 0; kk < 6; ++kk)
        wf[g][kk] = *(const f16x8*)(whh16 + ((((size_t)dir * 12 + w) * 4 + g) * 6 + kk) * 512 + l * 8);

    {
      f16* hz = (f16*)sm.hb;
      for (int i = tid; i < 2 * 16 * 200; i += 768) hz[i] = (f16)0.f;
    }
    __syncthreads();
    float cq[4] = {0.f, 0.f, 0.f, 0.f};

    // wait for chunk 0 (wave 0 polls, barrier releases), preload steps 0..2
    if (w == 0) {
      while (__ballot(ATL(done + (l & (nblk - 1))) != 0) != ~0ull)
        __builtin_amdgcn_s_sleep(8);
    }
    __builtin_amdgcn_s_barrier();

    u64 bA[4], bB[4], bC[4], bD[4];

#define LOADSTEP(SN, BUF)                                                          \
    do {                                                                           \
      int tl_ = (SN) & TCm1; if (dir) tl_ = TCm1 - tl_;                            \
      const u64* p_ = gxring + (size_t)(((SN) >> lgTC) & Rm1) * chunkQW +          \
                      (size_t)(dirT + tl_) * 49152 + segTid;                       \
      BUF[0] = ATL64(p_ + 0); BUF[1] = ATL64(p_ + 1);                              \
      BUF[2] = ATL64(p_ + 2); BUF[3] = ATL64(p_ + 3);                              \
    } while (0)

    LOADSTEP(0, bA);
    LOADSTEP(1, bB);
    LOADSTEP(2, bC);

#define RSTEP(S, CUR, NXT)                                                         \
  do {                                                                             \
    const int t = dir ? (511 - (S)) : (S);                                         \
    if (((S) & TCm1) == 0 && (S) != 0 && tid == 0)                                 \
      ATS(freed + ((((S) >> lgTC) - 1) << 5) + wg, 1);                             \
    const int sn = (S) + 3;                                                        \
    if (sn < 512) {                                                                \
      if ((sn & TCm1) == 0) {                                                      \
        if (w == 0) {                                                              \
          const int fi_ = ((sn >> lgTC) << lgNB) + (l & (nblk - 1));               \
          while (__ballot(ATL(done + fi_) != 0) != ~0ull)                          \
            __builtin_amdgcn_s_sleep(8);                                           \
        }                                                                          \
        __builtin_amdgcn_s_barrier();                                              \
      }                                                                            \
      LOADSTEP(sn, NXT);                                                           \
    }                                                                              \
    f32x4 ac[4] = {};                                                              \
    {                                                                              \
      const f16* hcur = sm.hb[(S) & 1];                                            \
      _Pragma("unroll") for (int kk = 0; kk < 6; ++kk) {                           \
        f16x8 av = *(const f16x8*)(hcur + lo16 * 200 + kk * 32 + lhi * 8);         \
        ac[0] = __builtin_amdgcn_mfma_f32_16x16x32_f16(av, wf[0][kk], ac[0], 0, 0, 0); \
        ac[1] = __builtin_amdgcn_mfma_f32_16x16x32_f16(av, wf[1][kk], ac[1], 0, 0, 0); \
        ac[2] = __builtin_amdgcn_mfma_f32_16x16x32_f16(av, wf[2][kk], ac[2], 0, 0, 0); \
        ac[3] = __builtin_amdgcn_mfma_f32_16x16x32_f16(av, wf[3][kk], ac[3], 0, 0, 0); \
      }                                                                            \
    }                                                                              \
    float z[4][4];                                                                 \
    _Pragma("unroll") for (int g_ = 0; g_ < 4; ++g_) {                             \
      union { u64 v; struct { u32 d0, d1; } d; } pk;                               \
      pk.v = CUR[g_];                                                              \
      union { u32 u; f16 h[2]; } p0, p1;                                           \
      p0.u = pk.d.d0; p1.u = pk.d.d1;                                              \
      z[g_][0] = ac[g_][0] + (float)p0.h[0];                                       \
      z[g_][1] = ac[g_][1] + (float)p0.h[1];                                       \
      z[g_][2] = ac[g_][2] + (float)p1.h[0];                                       \
      z[g_][3] = ac[g_][3] + (float)p1.h[1];                                       \
    }                                                                              \
    f16* hnew = sm.hb[((S) + 1) & 1];                                              \
    _Pragma("unroll") for (int q = 0; q < 4; ++q) {                                \
      float ei = __builtin_amdgcn_exp2f(fminf(z[0][q] * -1.44269504f, 80.f));      \
      float ef = __builtin_amdgcn_exp2f(fminf(z[1][q] * -1.44269504f, 80.f));      \
      float eg = __builtin_amdgcn_exp2f(fminf(z[2][q] * -2.88539008f, 80.f));      \
      float eo = __builtin_amdgcn_exp2f(fminf(z[3][q] * -1.44269504f, 80.f));      \
      float ig = (1.f - eg) * __builtin_amdgcn_rcpf((1.f + eg) * (1.f + ei));      \
      float fv = __builtin_amdgcn_rcpf(1.f + ef);                                  \
      cq[q] = fv * cq[q] + ig;                                                     \
      float ec = __builtin_amdgcn_exp2f(fminf(cq[q] * -2.88539008f, 80.f));        \
      float hv = (1.f - ec) * __builtin_amdgcn_rcpf((1.f + ec) * (1.f + eo));      \
      f16 hh = (f16)hv;                                                            \
      hnew[(lhi * 4 + q) * 200 + u0 + lo16] = hh;                                  \
      if (wOut) outh[((size_t)t * 256 + bb + q) * 384 + dc + u0 + lo16] = hh;      \
      if (wHT && (S) == 511)                                                       \
        hT[((size_t)dir * 256 + bb + q) * 192 + u0 + lo16] = hv;                   \
    }                                                                              \
    asm volatile("s_waitcnt lgkmcnt(0)" ::: "memory");                             \
    __builtin_amdgcn_s_barrier();                                                  \
    asm volatile("" ::: "memory");                                                 \
  } while (0)

    for (int s = 0; s < 512; s += 4) {  // PF=3 via 4 rotating buffers
      RSTEP(s, bA, bD);
      RSTEP(s + 1, bB, bA);
      RSTEP(s + 2, bC, bB);
      RSTEP(s + 3, bD, bC);
    }
#undef RSTEP
#undef LOADSTEP
    return;
  }

  // ================= GEMM producer: static map, 64-row tiles =================
  const int wmm = w / 6, wn = w % 6;  // 2x6 wave grid: 32 rows x 32 cols each
  constexpr int NKc = KD / 64;
  const int total = NC << lgNB;

  for (int bid = wg - 32; bid < total; bid += 224) {
    const int c = bid >> lgNB, blk = bid & (nblk - 1);
    if (c > Rm1) {  // wait for ring slot: freed[c-R] all 32 set (wave0 polls)
      if (w == 0) {
        const int fi = ((c - Rm1 - 1) << 5) + (l & 31);
        while (__ballot(ATL(freed + fi) != 0) != ~0ull) __builtin_amdgcn_s_sleep(32);
      }
      __syncthreads();
    }
    const int dir = blk >> (lgNB - 1);
    const int r = blk & ((nblk >> 1) - 1);   // 64-row tile idx, 4 per t
    const int t_loc = r >> 2;
    const int b0r = (r & 3) * 64;
    const int tg = dir ? (512 - (c + 1) * TC + t_loc) : (c * TC + t_loc);
    const size_t ar0 = (size_t)tg * 256 + b0r;
    u64* gxW = gxring + (size_t)(c & Rm1) * chunkQW;

    for (int g = 0; g < 4; ++g) {  // same A tile 4x -> L2-hot for g>0
      const int btr0 = dir * 768 + g * 192;
      float bj[2];
#pragma unroll
      for (int j = 0; j < 2; ++j) bj[j] = bias[btr0 + wn * 32 + j * 16 + lo16];

      f32x4 acc[2][2] = {};
      uint4 a0v, b0v, b1v;

#define LDG(ko_)                                                                   \
  do {                                                                             \
    if (tid < 512) {                                                               \
      int row = tid >> 3, sl = tid & 7, ch = sl ^ (row & 7);                       \
      a0v = *(const uint4*)(in + (ar0 + row) * KD + (ko_)*64 + ch * 8);            \
    }                                                                              \
    { int row = tid >> 3, sl = tid & 7, ch = sl ^ (row & 7);                       \
      b0v = *(const uint4*)(Bt + (size_t)(btr0 + row) * KD + (ko_)*64 + ch * 8); } \
    { int idx = tid + 768; int row = idx >> 3, sl = idx & 7, ch = sl ^ (row & 7);  \
      b1v = *(const uint4*)(Bt + (size_t)(btr0 + row) * KD + (ko_)*64 + ch * 8); } \
  } while (0)

      LDG(0);
      for (int ko = 0; ko < NKc; ++ko) {
        __syncthreads();
        if (tid < 512) sm.g.A[tid] = a0v;
        sm.g.B[tid] = b0v;
        sm.g.B[tid + 768] = b1v;
        __syncthreads();
        if (ko + 1 < NKc) LDG(ko + 1);
#pragma unroll
        for (int kk = 0; kk < 2; ++kk) {
          f16x8 af[2], bf[2];
#pragma unroll
          for (int i = 0; i < 2; ++i) {
            int rowA = wmm * 32 + i * 16 + lo16;
            int slA = (kk * 4 + lhi) ^ (rowA & 7);
            af[i] = *(const f16x8*)((const char*)sm.g.A + rowA * 128 + slA * 16);
          }
#pragma unroll
          for (int j = 0; j < 2; ++j) {
            int colB = wn * 32 + j * 16 + lo16;
            int slB = (kk * 4 + lhi) ^ (colB & 7);
            bf[j] = *(const f16x8*)((const char*)sm.g.B + colB * 128 + slB * 16);
          }
#pragma unroll
          for (int i = 0; i < 2; ++i)
#pragma unroll
            for (int j = 0; j < 2; ++j)
              acc[i][j] = __builtin_amdgcn_mfma_f32_16x16x32_f16(af[i], bf[j], acc[i][j], 0, 0, 0);
        }
      }
#undef LDG

      // epilogue -> gx ring slot (packed u64 agent stores)
#pragma unroll
      for (int i = 0; i < 2; ++i) {
        int rl = r * 64 + wmm * 32 + i * 16 + lhi * 4;
        int tl = rl >> 8;
        int b16 = (rl & 255) >> 4;
#pragma unroll
        for (int j = 0; j < 2; ++j) {
          int w12 = wn * 2 + j;
          size_t seg = (size_t)((dir * TC + tl) * 16 + b16) * 12 + w12;
          union { u32 u; f16 h[2]; } q0, q1;
          q0.h[0] = (f16)(acc[i][j][0] + bj[j]);
          q0.h[1] = (f16)(acc[i][j][1] + bj[j]);
          q1.h[0] = (f16)(acc[i][j][2] + bj[j]);
          q1.h[1] = (f16)(acc[i][j][3] + bj[j]);
          u64 pk = (u64)q0.u | ((u64)q1.u << 32);
          ATS64(gxW + seg * 256 + l * 4 + g, pk);
        }
      }
      __syncthreads();  // protect LDS reuse across gate loop
    }
    asm volatile("s_waitcnt vmcnt(0)" ::: "memory");  // drain this wave's stores
    __syncthreads();                                  // => all waves drained
    if (tid == 0) ATS(done + bid, 1);                 // single store, no RMW
  }
}

__global__ void fck(const float* __restrict__ hT, const float* __restrict__ w,
                    const float* __restrict__ fb, float* __restrict__ out) {
  int b = blockIdx.x * 64 + threadIdx.x;
  float a = fb[0];
#pragma unroll 4
  for (int u = 0; u < 192; ++u)
    a += w[u] * hT[(size_t)b * 192 + u] + w[192 + u] * hT[49152 + (size_t)b * 192 + u];
  out[b] = a;
}

extern "C" void kernel_launch(void* const* d_in, const int* in_sizes, int n_in,
                              void* d_out, int out_size, void* d_ws, size_t ws_size,
                              hipStream_t stream) {
  (void)in_sizes; (void)n_in; (void)out_size;
  const int* x = (const int*)d_in[0];
  const float* emb = (const float*)d_in[1];
  const float* Wih0 = (const float*)d_in[2];
  const float* Whh0 = (const float*)d_in[3];
  const float* b0 = (const float*)d_in[4];
  const float* Wihr = (const float*)d_in[5];
  const float* Whhr = (const float*)d_in[6];
  const float* br = (const float*)d_in[7];
  const float* fcw = (const float*)d_in[8];
  const float* fcb = (const float*)d_in[9];
  float* out = (float*)d_out;

  const size_t hB = 100663296ull;  // [512][256][384] f16
  const size_t fixedB = 2 * hB + 1179648ull + 589824ull + 393216ull + 65536ull;
  const size_t ringAvail = (ws_size > fixedB) ? (ws_size - fixedB) : 0;

  // ring ladder: POWER-OF-2 R only (slot = c & (R-1))
  int TC = 4, R = 4;  // 12.6 MB -- always fits the proven ws floor
  if (ringAvail >= 8ull * 4 * 786432ull) R = 8;  // 25.2 MB if ws allows
  const int NC = 512 / TC;
  const size_t chunkB = (size_t)TC * 786432ull;
  int lgTC = 31 - __builtin_clz((unsigned)TC);

  char* ws = (char*)d_ws;
  u64* gx = (u64*)ws;
  size_t off = (size_t)R * chunkB;
  f16* h0 = (f16*)(ws + off); off += hB;
  f16* h1 = (f16*)(ws + off); off += hB;
  f16* A0 = h1;  // alias: A0 fully consumed by layer-0 producers before layer-1 writes h1
  f16* Bt = (f16*)(ws + off); off += 1179648ull;     // [1536][KD] f16 (per-layer)
  f16* whh16 = (f16*)(ws + off); off += 589824ull;   // fragment layout (per-layer)
  float* hT = (float*)(ws + off); off += 393216ull;  // [2][256][192] f32
  int* flags = (int*)(ws + off);                     // done[4096] | freed[4096]

  embedk<<<16384, 256, 0, stream>>>(x, emb, A0);

  for (int layer = 0; layer < 3; ++layer) {
    const int wOut = (layer < 2) ? 1 : 0;
    const int wHT = (layer == 2) ? 1 : 0;
    const float* bias = (layer == 0) ? b0 : (br + (layer - 1) * 1536);

    if (layer == 0) {
      castk<<<192, 256, 0, stream>>>(Wih0, Bt, 196608);
      castwhh<<<1152, 256, 0, stream>>>(Whh0, whh16);
    } else {
      castk<<<1152, 256, 0, stream>>>(Wihr + (size_t)(layer - 1) * 589824, Bt, 589824);
      castwhh<<<1152, 256, 0, stream>>>(Whhr + (size_t)(layer - 1) * 294912, whh16);
    }
    zerok<<<64, 256, 0, stream>>>(flags);

    if (layer == 0)
      persistk<128><<<256, 768, 0, stream>>>(A0, Bt, b0, gx, whh16, h0, hT,
                                             flags, R - 1, NC, TC, lgTC, wOut, wHT);
    else if (layer == 1)
      persistk<384><<<256, 768, 0, stream>>>(h0, Bt, bias, gx, whh16, h1, hT,
                                             flags, R - 1, NC, TC, lgTC, wOut, wHT);
    else
      persistk<384><<<256, 768, 0, stream>>>(h1, Bt, bias, gx, whh16, h0, hT,
                                             flags, R - 1, NC, TC, lgTC, wOut, wHT);
  }

  fck<<<4, 64, 0, stream>>>(hT, fcw, fcb, out);
}

// Round 9
// 3736.633 us; speedup vs baseline: 1.3078x; 1.3078x over previous
//
#include <hip/hip_runtime.h>
#include <hip/hip_bf16.h>

// LSTM_66443144069713: 3-layer biLSTM, B=256 T=512 H=192 E=128, V=20000.
// Round-9: revert to round-3's launch-boundary pipeline (fused chunk launches,
// plain cached loads -- kernel-edge L2 flush gives free cross-XCD coherence;
// rounds 4-8 proved the sc1/MALL producer-consumer path is 3x slower).
// Upgrades vs round 3: fused gate math (8 trans/cell, r8-proven), PF=3 gx
// prefetch via 4 rotating buffers, u32 coalesced gx layout.

typedef _Float16 f16;
typedef unsigned int u32;
typedef _Float16 f16x8 __attribute__((ext_vector_type(8)));
typedef float f32x4 __attribute__((ext_vector_type(4)));

// ---------- small utility kernels ----------

__global__ void castk(const float* __restrict__ s, f16* __restrict__ d, int n) {
  int i = blockIdx.x * 256 + threadIdx.x;
  int st = gridDim.x * 256;
  for (; i < n; i += st) d[i] = (f16)s[i];
}

// W_hh (f32 [2][768][192]) -> f16 fragment layout [dir][w12][g][kk][lane][8]
__global__ void castwhh(const float* __restrict__ src, f16* __restrict__ dst) {
  int o = blockIdx.x * 256 + threadIdx.x;  // < 294912
  int e = o & 7, rest = o >> 3;
  int l = rest & 63; rest >>= 6;
  int kk = rest % 6; rest /= 6;
  int g = rest & 3; rest >>= 2;
  int w = rest % 12; int dir = rest / 12;
  int lo16 = l & 15, lhi = l >> 4;
  dst[o] = (f16)src[(size_t)(dir * 768 + g * 192 + w * 16 + lo16) * 192 + kk * 32 + lhi * 8 + e];
}

// A0[t*256+b][k] = fp16(emb[x[b][t]][k])
__global__ void embedk(const int* __restrict__ x, const float* __restrict__ emb,
                       f16* __restrict__ A0) {
  int row = blockIdx.x * 8 + (threadIdx.x >> 5);
  int t = row >> 8, b = row & 255;
  int xi = x[b * 512 + t];
  int c = (threadIdx.x & 31) * 4;
  float4 v = *(const float4*)(emb + (size_t)xi * 128 + c);
  union { f16 h[4]; uint2 u; } p;
  p.h[0] = (f16)v.x; p.h[1] = (f16)v.y; p.h[2] = (f16)v.z; p.h[3] = (f16)v.w;
  *(uint2*)(A0 + (size_t)row * 128 + c) = p.u;
}

// ---------- fused kernel ----------
// gx dword index: ((((dir*TC+tl)*16 + b16)*12 + w12)*512) + (g*2+qq)*64 + lane,
//   lane = ((b&15)>>2)*16 + (u&15); dword packs batch rows 2qq (lo), 2qq+1 (hi).
template <int KD>
__global__ __launch_bounds__(768)
void fusedk(const f16* __restrict__ in, const f16* __restrict__ Bt,
            const float* __restrict__ bias,
            const u32* __restrict__ gxR, u32* __restrict__ gxW,
            const f16* __restrict__ whh16,
            f16* __restrict__ outh, float* __restrict__ hT,
            f16* __restrict__ carh, float* __restrict__ carc,
            int c, int cg, int NC, int TC, int doLstm, int wOut, int wHT) {
  union SMem {
    struct { uint4 A[1024]; uint4 B[1536]; } g;   // 16KB + 24KB
    f16 hb[2][16 * 200];                          // 12.8KB
  };
  __shared__ __align__(16) SMem sm;
  const int wg = blockIdx.x;
  const int tid = threadIdx.x;
  const int l = tid & 63, w = tid >> 6;
  const int lo16 = l & 15, lhi = l >> 4;
  const int TCm1 = TC - 1;

  if (doLstm && wg < 32) {
    // ================= recurrence part (chunk c) =================
    const int dir = wg & 1, bblk = wg >> 1;
    const int u0 = w * 16;
    const int bb = bblk * 16 + lhi * 4;
    const int dc = dir * 192;

    f16x8 wf[4][6];
#pragma unroll
    for (int g = 0; g < 4; ++g)
#pragma unroll
      for (int kk = 0; kk < 6; ++kk)
        wf[g][kk] = *(const f16x8*)(whh16 + ((((size_t)dir * 12 + w) * 4 + g) * 6 + kk) * 512 + l * 8);

    float cq[4];
    if (c == 0) {
      f16* hz = (f16*)sm.hb;
      for (int i = tid; i < 2 * 16 * 200; i += 768) hz[i] = (f16)0.f;
#pragma unroll
      for (int q = 0; q < 4; ++q) cq[q] = 0.f;
    } else {
#pragma unroll
      for (int q = 0; q < 4; ++q) {
        size_t ci = ((size_t)dir * 256 + bb + q) * 192 + u0 + lo16;
        cq[q] = carc[ci];
        sm.hb[0][(lhi * 4 + q) * 200 + u0 + lo16] = carh[ci];
      }
    }
    __syncthreads();

    u32 bA[8], bB[8], bC[8], bD[8];

#define LOADSTEP(SL, BUF)                                                          \
    do {                                                                           \
      int sl_ = (SL) < TCm1 ? (SL) : TCm1;                                         \
      int tl_ = dir ? (TCm1 - sl_) : sl_;                                          \
      size_t wb_ = ((((size_t)dir * TC + tl_) * 16 + bblk) * 12 + w) * 512;        \
      _Pragma("unroll") for (int k2 = 0; k2 < 8; ++k2)                             \
        BUF[k2] = gxR[wb_ + k2 * 64 + l];                                          \
    } while (0)

    LOADSTEP(0, bA);
    LOADSTEP(1, bB);
    LOADSTEP(2, bC);

    const int tb0 = dir ? (511 - c * TC) : (c * TC);

#define RSTEP(S, CUR, NXT)                                                         \
  do {                                                                             \
    const int t = dir ? (tb0 - (S)) : (tb0 + (S));                                 \
    LOADSTEP((S) + 3, NXT);                                                        \
    f32x4 ac[4] = {};                                                              \
    {                                                                              \
      const f16* hcur = sm.hb[(S) & 1];                                            \
      _Pragma("unroll") for (int kk = 0; kk < 6; ++kk) {                           \
        f16x8 av = *(const f16x8*)(hcur + lo16 * 200 + kk * 32 + lhi * 8);         \
        ac[0] = __builtin_amdgcn_mfma_f32_16x16x32_f16(av, wf[0][kk], ac[0], 0, 0, 0); \
        ac[1] = __builtin_amdgcn_mfma_f32_16x16x32_f16(av, wf[1][kk], ac[1], 0, 0, 0); \
        ac[2] = __builtin_amdgcn_mfma_f32_16x16x32_f16(av, wf[2][kk], ac[2], 0, 0, 0); \
        ac[3] = __builtin_amdgcn_mfma_f32_16x16x32_f16(av, wf[3][kk], ac[3], 0, 0, 0); \
      }                                                                            \
    }                                                                              \
    float z[4][4];                                                                 \
    _Pragma("unroll") for (int k2 = 0; k2 < 8; ++k2) {                             \
      union { u32 u; f16 h[2]; } p;                                                \
      p.u = CUR[k2];                                                               \
      const int g_ = k2 >> 1, qq_ = k2 & 1;                                        \
      z[g_][2 * qq_] = ac[g_][2 * qq_] + (float)p.h[0];                            \
      z[g_][2 * qq_ + 1] = ac[g_][2 * qq_ + 1] + (float)p.h[1];                    \
    }                                                                              \
    f16* hnew = sm.hb[((S) + 1) & 1];                                              \
    _Pragma("unroll") for (int q = 0; q < 4; ++q) {                                \
      float ei = __builtin_amdgcn_exp2f(fminf(z[0][q] * -1.44269504f, 80.f));      \
      float ef = __builtin_amdgcn_exp2f(fminf(z[1][q] * -1.44269504f, 80.f));      \
      float eg = __builtin_amdgcn_exp2f(fminf(z[2][q] * -2.88539008f, 80.f));      \
      float eo = __builtin_amdgcn_exp2f(fminf(z[3][q] * -1.44269504f, 80.f));      \
      float ig = (1.f - eg) * __builtin_amdgcn_rcpf((1.f + eg) * (1.f + ei));      \
      float fv = __builtin_amdgcn_rcpf(1.f + ef);                                  \
      cq[q] = fv * cq[q] + ig;                                                     \
      float ec = __builtin_amdgcn_exp2f(fminf(cq[q] * -2.88539008f, 80.f));        \
      float hv = (1.f - ec) * __builtin_amdgcn_rcpf((1.f + ec) * (1.f + eo));      \
      f16 hh = (f16)hv;                                                            \
      hnew[(lhi * 4 + q) * 200 + u0 + lo16] = hh;                                  \
      if (wOut) outh[((size_t)t * 256 + bb + q) * 384 + dc + u0 + lo16] = hh;      \
      if ((S) == TCm1) {                                                           \
        size_t ci = ((size_t)dir * 256 + bb + q) * 192 + u0 + lo16;                \
        carh[ci] = hh;                                                             \
        carc[ci] = cq[q];                                                          \
        if (wHT && c == NC - 1) hT[ci] = hv;                                       \
      }                                                                            \
    }                                                                              \
    asm volatile("s_waitcnt lgkmcnt(0)" ::: "memory");                             \
    __builtin_amdgcn_s_barrier();                                                  \
    asm volatile("" ::: "memory");                                                 \
  } while (0)

    for (int s = 0; s < TC; s += 4) {  // PF=3 via 4 rotating buffers; TC % 4 == 0
      RSTEP(s, bA, bD);
      RSTEP(s + 1, bB, bA);
      RSTEP(s + 2, bC, bB);
      RSTEP(s + 3, bD, bC);
    }
#undef RSTEP
#undef LOADSTEP
    return;
  }

  // ================= GEMM part (chunk cg -> gxW) =================
  if (cg >= NC) return;
  const int pool = doLstm ? 224 : 256;
  const int gid = doLstm ? wg - 32 : wg;
  const int RT = TC * 2;          // 128-row tiles per direction
  const int ntiles = RT * 8;      // 2 dirs * RT * 4 gates
  const int tbf = cg * TC, tbb = 512 - (cg + 1) * TC;
  const int wmm = w / 6, wn = w % 6;
  constexpr int NKc = KD / 64;

  for (int tt = gid; tt < ntiles; tt += pool) {
    const int g = tt & 3;
    const int r = (tt >> 2) % RT;
    const int dir = (tt >> 2) / RT;
    const size_t ar0 = (size_t)(dir ? tbb : tbf) * 256 + r * 128;  // A row base
    const int btr0 = dir * 768 + g * 192;                          // Bt row base

    float bj[2];
#pragma unroll
    for (int j = 0; j < 2; ++j) bj[j] = bias[btr0 + wn * 32 + j * 16 + lo16];

    f32x4 acc[4][2] = {};
    uint4 a0, a1, b0, b1;

#define LDG(ko_)                                                                   \
  do {                                                                             \
    { int idx = tid; int row = idx >> 3, sl = idx & 7; int ch = sl ^ (row & 7);    \
      a0 = *(const uint4*)(in + (ar0 + row) * KD + (ko_)*64 + ch * 8); }           \
    if (tid < 256) { int idx = tid + 768; int row = idx >> 3, sl = idx & 7;        \
      int ch = sl ^ (row & 7);                                                     \
      a1 = *(const uint4*)(in + (ar0 + row) * KD + (ko_)*64 + ch * 8); }           \
    { int idx = tid; int row = idx >> 3, sl = idx & 7; int ch = sl ^ (row & 7);    \
      b0 = *(const uint4*)(Bt + (size_t)(btr0 + row) * KD + (ko_)*64 + ch * 8); }  \
    { int idx = tid + 768; int row = idx >> 3, sl = idx & 7; int ch = sl ^ (row & 7); \
      b1 = *(const uint4*)(Bt + (size_t)(btr0 + row) * KD + (ko_)*64 + ch * 8); }  \
  } while (0)

    LDG(0);
    for (int ko = 0; ko < NKc; ++ko) {
      __syncthreads();
      sm.g.A[tid] = a0;
      if (tid < 256) sm.g.A[tid + 768] = a1;
      sm.g.B[tid] = b0;
      sm.g.B[tid + 768] = b1;
      __syncthreads();
      if (ko + 1 < NKc) LDG(ko + 1);
#pragma unroll
      for (int kk = 0; kk < 2; ++kk) {
        f16x8 af[4], bf[2];
#pragma unroll
        for (int i = 0; i < 4; ++i) {
          int rowA = wmm * 64 + i * 16 + lo16;
          int slA = (kk * 4 + lhi) ^ (rowA & 7);
          af[i] = *(const f16x8*)((const char*)sm.g.A + rowA * 128 + slA * 16);
        }
#pragma unroll
        for (int j = 0; j < 2; ++j) {
          int colB = wn * 32 + j * 16 + lo16;
          int slB = (kk * 4 + lhi) ^ (colB & 7);
          bf[j] = *(const f16x8*)((const char*)sm.g.B + colB * 128 + slB * 16);
        }
#pragma unroll
        for (int i = 0; i < 4; ++i)
#pragma unroll
          for (int j = 0; j < 2; ++j)
            acc[i][j] = __builtin_amdgcn_mfma_f32_16x16x32_f16(af[i], bf[j], acc[i][j], 0, 0, 0);
      }
    }
#undef LDG

    // epilogue -> gxW (coalesced u32 stores)
#pragma unroll
    for (int i = 0; i < 4; ++i) {
      int rl = r * 128 + wmm * 64 + i * 16 + lhi * 4;  // local row; q adds 0..3
      int tl = rl >> 8;
      int b16 = (rl & 255) >> 4;
#pragma unroll
      for (int j = 0; j < 2; ++j) {
        int w12 = wn * 2 + j;
        size_t base = ((((size_t)dir * TC + tl) * 16 + b16) * 12 + w12) * 512;
#pragma unroll
        for (int qq = 0; qq < 2; ++qq) {
          union { f16 h[2]; u32 u; } p;
          p.h[0] = (f16)(acc[i][j][2 * qq] + bj[j]);
          p.h[1] = (f16)(acc[i][j][2 * qq + 1] + bj[j]);
          gxW[base + (g * 2 + qq) * 64 + l] = p.u;
        }
      }
    }
    __syncthreads();  // protect LDS reuse across tile loop
  }
}

__global__ void fck(const float* __restrict__ hT, const float* __restrict__ w,
                    const float* __restrict__ fb, float* __restrict__ out) {
  int b = blockIdx.x * 64 + threadIdx.x;
  float a = fb[0];
#pragma unroll 4
  for (int u = 0; u < 192; ++u)
    a += w[u] * hT[(size_t)b * 192 + u] + w[192 + u] * hT[49152 + (size_t)b * 192 + u];
  out[b] = a;
}

extern "C" void kernel_launch(void* const* d_in, const int* in_sizes, int n_in,
                              void* d_out, int out_size, void* d_ws, size_t ws_size,
                              hipStream_t stream) {
  (void)in_sizes; (void)n_in; (void)out_size;
  const int* x = (const int*)d_in[0];
  const float* emb = (const float*)d_in[1];
  const float* Wih0 = (const float*)d_in[2];
  const float* Whh0 = (const float*)d_in[3];
  const float* b0 = (const float*)d_in[4];
  const float* Wihr = (const float*)d_in[5];
  const float* Whhr = (const float*)d_in[6];
  const float* br = (const float*)d_in[7];
  const float* fcw = (const float*)d_in[8];
  const float* fcb = (const float*)d_in[9];
  float* out = (float*)d_out;

  const size_t hB = 100663296ull;  // [512][256][384] f16
  const size_t fixedB = 2 * hB + 1179648ull + 589824ull + 393216ull + 196608ull + 393216ull;

  int TC = (ws_size >= fixedB + 2ull * 16 * 786432ull) ? 16 : 8;  // r3 proved TC=16 fits
  const int NC = 512 / TC;
  const size_t chunkB = (size_t)TC * 786432ull;

  char* ws = (char*)d_ws;
  u32* gxb[2] = {(u32*)ws, (u32*)(ws + chunkB)};
  size_t off = 2 * chunkB;
  f16* h0 = (f16*)(ws + off); off += hB;
  f16* h1 = (f16*)(ws + off); off += hB;
  f16* A0 = h1;  // alias: A0 dead before h1's first write (layer-1 lstm)
  f16* Bt = (f16*)(ws + off); off += 1179648ull;     // [1536][KD] f16 (per-layer)
  f16* whh16 = (f16*)(ws + off); off += 589824ull;   // fragment layout (per-layer)
  float* hT = (float*)(ws + off); off += 393216ull;  // [2][256][192] f32
  f16* carh = (f16*)(ws + off); off += 196608ull;
  float* carc = (float*)(ws + off); off += 393216ull;

  embedk<<<16384, 256, 0, stream>>>(x, emb, A0);

  for (int layer = 0; layer < 3; ++layer) {
    const f16* in = (layer == 0) ? A0 : (layer == 1 ? h0 : h1);
    f16* outp = (layer == 1) ? h1 : h0;  // layer 2: unused (wOut=0)
    const int wOut = (layer < 2) ? 1 : 0;
    const int wHT = (layer == 2) ? 1 : 0;
    const float* bias = (layer == 0) ? b0 : (br + (layer - 1) * 1536);

    if (layer == 0) {
      castk<<<192, 256, 0, stream>>>(Wih0, Bt, 196608);
      castwhh<<<1152, 256, 0, stream>>>(Whh0, whh16);
    } else {
      castk<<<1152, 256, 0, stream>>>(Wihr + (size_t)(layer - 1) * 589824, Bt, 589824);
      castwhh<<<1152, 256, 0, stream>>>(Whhr + (size_t)(layer - 1) * 294912, whh16);
    }

    // prologue: gemm chunk 0 with all 256 WGs
    if (layer == 0)
      fusedk<128><<<256, 768, 0, stream>>>(in, Bt, bias, gxb[0], gxb[0], whh16,
                                           outp, hT, carh, carc, 0, 0, NC, TC, 0, wOut, wHT);
    else
      fusedk<384><<<256, 768, 0, stream>>>(in, Bt, bias, gxb[0], gxb[0], whh16,
                                           outp, hT, carh, carc, 0, 0, NC, TC, 0, wOut, wHT);

    for (int c = 0; c < NC; ++c) {
      const u32* gR = gxb[c & 1];
      u32* gW = gxb[(c + 1) & 1];
      if (layer == 0)
        fusedk<128><<<256, 768, 0, stream>>>(in, Bt, bias, gR, gW, whh16,
                                             outp, hT, carh, carc, c, c + 1, NC, TC, 1, wOut, wHT);
      else
        fusedk<384><<<256, 768, 0, stream>>>(in, Bt, bias, gR, gW, whh16,
                                             outp, hT, carh, carc, c, c + 1, NC, TC, 1, wOut, wHT);
    }
  }

  fck<<<4, 64, 0, stream>>>(hT, fcw, fcb, out);
}

// Round 10
// 2779.458 us; speedup vs baseline: 1.7582x; 1.3444x over previous
//
#include <hip/hip_runtime.h>
#include <hip/hip_bf16.h>

// LSTM_66443144069713: 3-layer biLSTM, B=256 T=512 H=192 E=128, V=20000.
// Round-10: r3's launch-boundary chunk pipeline (proven fastest) with the
// r3-exact PF=1 lstm inner loop restored (r9's PF=3/fused-trans regressed).
// Trims: MFMA accumulator seeded with gx (no separate z add), incremental
// outh pointer, 64-row gemm tiles for tail balance (512 tiles / 224 WGs).

typedef _Float16 f16;
typedef unsigned int u32;
typedef _Float16 f16x8 __attribute__((ext_vector_type(8)));
typedef float f32x4 __attribute__((ext_vector_type(4)));

__device__ __forceinline__ float sigm(float x) {
  float e = __builtin_amdgcn_exp2f(x * -1.44269504088896f);
  return __builtin_amdgcn_rcpf(1.0f + e);
}
__device__ __forceinline__ float tanh_(float x) {
  float e = __builtin_amdgcn_exp2f(x * -2.88539008177793f);
  return __builtin_fmaf(2.0f, __builtin_amdgcn_rcpf(1.0f + e), -1.0f);
}

// ---------- small utility kernels ----------

__global__ void castk(const float* __restrict__ s, f16* __restrict__ d, int n) {
  int i = blockIdx.x * 256 + threadIdx.x;
  int st = gridDim.x * 256;
  for (; i < n; i += st) d[i] = (f16)s[i];
}

// W_hh (f32 [2][768][192]) -> f16 fragment layout [dir][w12][g][kk][lane][8]
__global__ void castwhh(const float* __restrict__ src, f16* __restrict__ dst) {
  int o = blockIdx.x * 256 + threadIdx.x;  // < 294912
  int e = o & 7, rest = o >> 3;
  int l = rest & 63; rest >>= 6;
  int kk = rest % 6; rest /= 6;
  int g = rest & 3; rest >>= 2;
  int w = rest % 12; int dir = rest / 12;
  int lo16 = l & 15, lhi = l >> 4;
  dst[o] = (f16)src[(size_t)(dir * 768 + g * 192 + w * 16 + lo16) * 192 + kk * 32 + lhi * 8 + e];
}

// A0[t*256+b][k] = fp16(emb[x[b][t]][k])
__global__ void embedk(const int* __restrict__ x, const float* __restrict__ emb,
                       f16* __restrict__ A0) {
  int row = blockIdx.x * 8 + (threadIdx.x >> 5);
  int t = row >> 8, b = row & 255;
  int xi = x[b * 512 + t];
  int c = (threadIdx.x & 31) * 4;
  float4 v = *(const float4*)(emb + (size_t)xi * 128 + c);
  union { f16 h[4]; uint2 u; } p;
  p.h[0] = (f16)v.x; p.h[1] = (f16)v.y; p.h[2] = (f16)v.z; p.h[3] = (f16)v.w;
  *(uint2*)(A0 + (size_t)row * 128 + c) = p.u;
}

// ---------- fused kernel ----------
// gx dword index: ((((dir*TC+tl)*16 + b16)*12 + w12)*512) + (g*2+qq)*64 + lane,
//   lane = ((b&15)>>2)*16 + (u&15); dword packs batch rows 2qq (lo), 2qq+1 (hi).
template <int KD>
__global__ __launch_bounds__(768)
void fusedk(const f16* __restrict__ in, const f16* __restrict__ Bt,
            const float* __restrict__ bias,
            const u32* __restrict__ gxR, u32* __restrict__ gxW,
            const f16* __restrict__ whh16,
            f16* __restrict__ outh, float* __restrict__ hT,
            f16* __restrict__ carh, float* __restrict__ carc,
            int c, int cg, int NC, int TC, int doLstm, int wOut, int wHT) {
  union SMem {
    struct { uint4 A[512]; uint4 B[1536]; } g;   // 8KB + 24KB gemm staging
    f16 hb[2][16 * 200];                         // 12.8KB recurrence h
  };
  __shared__ __align__(16) SMem sm;
  const int wg = blockIdx.x;
  const int tid = threadIdx.x;
  const int l = tid & 63, w = tid >> 6;
  const int lo16 = l & 15, lhi = l >> 4;
  const int TCm1 = TC - 1;

  if (doLstm && wg < 32) {
    // ================= recurrence part (chunk c) =================
    const int dir = wg & 1, bblk = wg >> 1;
    const int u0 = w * 16;
    const int bb = bblk * 16 + lhi * 4;
    const int dc = dir * 192;
    const int hb0 = lhi * 800 + u0 + lo16;  // (lhi*4)*200 + ...

    f16x8 wf[4][6];
#pragma unroll
    for (int g = 0; g < 4; ++g)
#pragma unroll
      for (int kk = 0; kk < 6; ++kk)
        wf[g][kk] = *(const f16x8*)(whh16 + ((((size_t)dir * 12 + w) * 4 + g) * 6 + kk) * 512 + l * 8);

    float cq[4];
    if (c == 0) {
      f16* hz = (f16*)sm.hb;
      for (int i = tid; i < 2 * 16 * 200; i += 768) hz[i] = (f16)0.f;
#pragma unroll
      for (int q = 0; q < 4; ++q) cq[q] = 0.f;
    } else {
#pragma unroll
      for (int q = 0; q < 4; ++q) {
        size_t ci = ((size_t)dir * 256 + bb + q) * 192 + u0 + lo16;
        cq[q] = carc[ci];
        sm.hb[0][(lhi * 4 + q) * 200 + u0 + lo16] = carh[ci];
      }
    }
    __syncthreads();

    const int tb0 = dir ? (511 - c * TC) : (c * TC);
    f16* outp = outh + ((size_t)tb0 * 256 + bb) * 384 + dc + u0 + lo16;
    const ptrdiff_t ostep = dir ? -(ptrdiff_t)98304 : (ptrdiff_t)98304;

    u32 ga[8], gb[8];
    {  // prefetch step 0
      const int tl0 = dir ? TCm1 : 0;
      size_t wb = ((((size_t)dir * TC + tl0) * 16 + bblk) * 12 + w) * 512;
#pragma unroll
      for (int k2 = 0; k2 < 8; ++k2) ga[k2] = gxR[wb + k2 * 64 + l];
    }

#define RSTEP(S, CUR, NXT)                                                         \
  do {                                                                             \
    {                                                                              \
      int snx = ((S) + 1 < TC) ? (S) + 1 : (S);                                    \
      int tln = dir ? (TCm1 - snx) : snx;                                          \
      size_t wb = ((((size_t)dir * TC + tln) * 16 + bblk) * 12 + w) * 512;         \
      _Pragma("unroll") for (int k2 = 0; k2 < 8; ++k2) NXT[k2] = gxR[wb + k2 * 64 + l]; \
    }                                                                              \
    f32x4 ac[4];                                                                   \
    _Pragma("unroll") for (int g_ = 0; g_ < 4; ++g_) {                             \
      union { u32 u; f16 h[2]; } p0, p1;                                           \
      p0.u = CUR[2 * g_]; p1.u = CUR[2 * g_ + 1];                                  \
      ac[g_][0] = (float)p0.h[0]; ac[g_][1] = (float)p0.h[1];                      \
      ac[g_][2] = (float)p1.h[0]; ac[g_][3] = (float)p1.h[1];                      \
    }                                                                              \
    {                                                                              \
      const f16* hcur = sm.hb[(S) & 1];                                            \
      _Pragma("unroll") for (int kk = 0; kk < 6; ++kk) {                           \
        f16x8 av = *(const f16x8*)(hcur + lo16 * 200 + kk * 32 + lhi * 8);         \
        ac[0] = __builtin_amdgcn_mfma_f32_16x16x32_f16(av, wf[0][kk], ac[0], 0, 0, 0); \
        ac[1] = __builtin_amdgcn_mfma_f32_16x16x32_f16(av, wf[1][kk], ac[1], 0, 0, 0); \
        ac[2] = __builtin_amdgcn_mfma_f32_16x16x32_f16(av, wf[2][kk], ac[2], 0, 0, 0); \
        ac[3] = __builtin_amdgcn_mfma_f32_16x16x32_f16(av, wf[3][kk], ac[3], 0, 0, 0); \
      }                                                                            \
    }                                                                              \
    f16* hnew = sm.hb[((S) + 1) & 1];                                              \
    _Pragma("unroll") for (int q = 0; q < 4; ++q) {                                \
      float iv = sigm(ac[0][q]), fv = sigm(ac[1][q]);                              \
      float gv = tanh_(ac[2][q]), ov = sigm(ac[3][q]);                             \
      cq[q] = fv * cq[q] + iv * gv;                                                \
      float hv = ov * tanh_(cq[q]);                                                \
      f16 hh = (f16)hv;                                                            \
      hnew[hb0 + q * 200] = hh;                                                    \
      if (wOut) outp[q * 384] = hh;                                                \
      if ((S) == TCm1) {                                                           \
        size_t ci = ((size_t)dir * 256 + bb + q) * 192 + u0 + lo16;                \
        carh[ci] = hh;                                                             \
        carc[ci] = cq[q];                                                          \
        if (wHT && c == NC - 1) hT[ci] = hv;                                       \
      }                                                                            \
    }                                                                              \
    outp += ostep;                                                                 \
    asm volatile("s_waitcnt lgkmcnt(0)" ::: "memory");                             \
    __builtin_amdgcn_s_barrier();                                                  \
    asm volatile("" ::: "memory");                                                 \
  } while (0)

    for (int s = 0; s < TC; s += 2) {
      RSTEP(s, ga, gb);
      RSTEP(s + 1, gb, ga);
    }
#undef RSTEP
    return;
  }

  // ================= GEMM part (chunk cg -> gxW), 64-row tiles =================
  if (cg >= NC) return;
  const int pool = doLstm ? 224 : 256;
  const int gid = doLstm ? wg - 32 : wg;
  const int RT = TC * 4;          // 64-row tiles per direction
  const int ntiles = RT * 8;      // 2 dirs * RT * 4 gates
  const int tbf = cg * TC, tbb = 512 - (cg + 1) * TC;
  const int wmm = w / 6, wn = w % 6;  // 2x6 waves: 32 rows x 32 cols each
  constexpr int NKc = KD / 64;

  for (int tt = gid; tt < ntiles; tt += pool) {
    const int g = tt & 3;
    const int r = (tt >> 2) % RT;
    const int dir = (tt >> 2) / RT;
    const size_t ar0 = (size_t)(dir ? tbb : tbf) * 256 + r * 64;  // A row base
    const int btr0 = dir * 768 + g * 192;                         // Bt row base

    float bj[2];
#pragma unroll
    for (int j = 0; j < 2; ++j) bj[j] = bias[btr0 + wn * 32 + j * 16 + lo16];

    f32x4 acc[2][2] = {};
    uint4 a0v, b0v, b1v;

#define LDG(ko_)                                                                   \
  do {                                                                             \
    if (tid < 512) {                                                               \
      int row = tid >> 3, sl = tid & 7, ch = sl ^ (row & 7);                       \
      a0v = *(const uint4*)(in + (ar0 + row) * KD + (ko_)*64 + ch * 8);            \
    }                                                                              \
    { int row = tid >> 3, sl = tid & 7, ch = sl ^ (row & 7);                       \
      b0v = *(const uint4*)(Bt + (size_t)(btr0 + row) * KD + (ko_)*64 + ch * 8); } \
    { int idx = tid + 768; int row = idx >> 3, sl = idx & 7, ch = sl ^ (row & 7);  \
      b1v = *(const uint4*)(Bt + (size_t)(btr0 + row) * KD + (ko_)*64 + ch * 8); } \
  } while (0)

    LDG(0);
    for (int ko = 0; ko < NKc; ++ko) {
      __syncthreads();
      if (tid < 512) sm.g.A[tid] = a0v;
      sm.g.B[tid] = b0v;
      sm.g.B[tid + 768] = b1v;
      __syncthreads();
      if (ko + 1 < NKc) LDG(ko + 1);
#pragma unroll
      for (int kk = 0; kk < 2; ++kk) {
        f16x8 af[2], bf[2];
#pragma unroll
        for (int i = 0; i < 2; ++i) {
          int rowA = wmm * 32 + i * 16 + lo16;
          int slA = (kk * 4 + lhi) ^ (rowA & 7);
          af[i] = *(const f16x8*)((const char*)sm.g.A + rowA * 128 + slA * 16);
        }
#pragma unroll
        for (int j = 0; j < 2; ++j) {
          int colB = wn * 32 + j * 16 + lo16;
          int slB = (kk * 4 + lhi) ^ (colB & 7);
          bf[j] = *(const f16x8*)((const char*)sm.g.B + colB * 128 + slB * 16);
        }
#pragma unroll
        for (int i = 0; i < 2; ++i)
#pragma unroll
          for (int j = 0; j < 2; ++j)
            acc[i][j] = __builtin_amdgcn_mfma_f32_16x16x32_f16(af[i], bf[j], acc[i][j], 0, 0, 0);
      }
    }
#undef LDG

    // epilogue -> gxW (coalesced u32 stores)
#pragma unroll
    for (int i = 0; i < 2; ++i) {
      int rl = r * 64 + wmm * 32 + i * 16 + lhi * 4;
      int tl = rl >> 8;
      int b16 = (rl & 255) >> 4;
#pragma unroll
      for (int j = 0; j < 2; ++j) {
        int w12 = wn * 2 + j;
        size_t base = ((((size_t)dir * TC + tl) * 16 + b16) * 12 + w12) * 512;
#pragma unroll
        for (int qq = 0; qq < 2; ++qq) {
          union { f16 h[2]; u32 u; } p;
          p.h[0] = (f16)(acc[i][j][2 * qq] + bj[j]);
          p.h[1] = (f16)(acc[i][j][2 * qq + 1] + bj[j]);
          gxW[base + (g * 2 + qq) * 64 + l] = p.u;
        }
      }
    }
    __syncthreads();  // protect LDS reuse across tile loop
  }
}

__global__ void fck(const float* __restrict__ hT, const float* __restrict__ w,
                    const float* __restrict__ fb, float* __restrict__ out) {
  int b = blockIdx.x * 64 + threadIdx.x;
  float a = fb[0];
#pragma unroll 4
  for (int u = 0; u < 192; ++u)
    a += w[u] * hT[(size_t)b * 192 + u] + w[192 + u] * hT[49152 + (size_t)b * 192 + u];
  out[b] = a;
}

extern "C" void kernel_launch(void* const* d_in, const int* in_sizes, int n_in,
                              void* d_out, int out_size, void* d_ws, size_t ws_size,
                              hipStream_t stream) {
  (void)in_sizes; (void)n_in; (void)out_size;
  const int* x = (const int*)d_in[0];
  const float* emb = (const float*)d_in[1];
  const float* Wih0 = (const float*)d_in[2];
  const float* Whh0 = (const float*)d_in[3];
  const float* b0 = (const float*)d_in[4];
  const float* Wihr = (const float*)d_in[5];
  const float* Whhr = (const float*)d_in[6];
  const float* br = (const float*)d_in[7];
  const float* fcw = (const float*)d_in[8];
  const float* fcb = (const float*)d_in[9];
  float* out = (float*)d_out;

  const size_t hB = 100663296ull;  // [512][256][384] f16
  const size_t fixedB = 2 * hB + 1179648ull + 589824ull + 393216ull + 196608ull + 393216ull;

  int TC = (ws_size >= fixedB + 2ull * 16 * 786432ull) ? 16 : 8;  // r3 proved TC=16 fits
  const int NC = 512 / TC;
  const size_t chunkB = (size_t)TC * 786432ull;

  char* ws = (char*)d_ws;
  u32* gxb[2] = {(u32*)ws, (u32*)(ws + chunkB)};
  size_t off = 2 * chunkB;
  f16* h0 = (f16*)(ws + off); off += hB;
  f16* h1 = (f16*)(ws + off); off += hB;
  f16* A0 = h1;  // alias: A0 dead before h1's first write (layer-1 lstm)
  f16* Bt = (f16*)(ws + off); off += 1179648ull;     // [1536][KD] f16 (per-layer)
  f16* whh16 = (f16*)(ws + off); off += 589824ull;   // fragment layout (per-layer)
  float* hT = (float*)(ws + off); off += 393216ull;  // [2][256][192] f32
  f16* carh = (f16*)(ws + off); off += 196608ull;
  float* carc = (float*)(ws + off); off += 393216ull;

  embedk<<<16384, 256, 0, stream>>>(x, emb, A0);

  for (int layer = 0; layer < 3; ++layer) {
    const f16* in = (layer == 0) ? A0 : (layer == 1 ? h0 : h1);
    f16* outp = (layer == 1) ? h1 : h0;  // layer 2: unused (wOut=0)
    const int wOut = (layer < 2) ? 1 : 0;
    const int wHT = (layer == 2) ? 1 : 0;
    const float* bias = (layer == 0) ? b0 : (br + (layer - 1) * 1536);

    if (layer == 0) {
      castk<<<192, 256, 0, stream>>>(Wih0, Bt, 196608);
      castwhh<<<1152, 256, 0, stream>>>(Whh0, whh16);
    } else {
      castk<<<1152, 256, 0, stream>>>(Wihr + (size_t)(layer - 1) * 589824, Bt, 589824);
      castwhh<<<1152, 256, 0, stream>>>(Whhr + (size_t)(layer - 1) * 294912, whh16);
    }

    // prologue: gemm chunk 0 with all 256 WGs
    if (layer == 0)
      fusedk<128><<<256, 768, 0, stream>>>(in, Bt, bias, gxb[0], gxb[0], whh16,
                                           outp, hT, carh, carc, 0, 0, NC, TC, 0, wOut, wHT);
    else
      fusedk<384><<<256, 768, 0, stream>>>(in, Bt, bias, gxb[0], gxb[0], whh16,
                                           outp, hT, carh, carc, 0, 0, NC, TC, 0, wOut, wHT);

    for (int c = 0; c < NC; ++c) {
      const u32* gR = gxb[c & 1];
      u32* gW = gxb[(c + 1) & 1];
      if (layer == 0)
        fusedk<128><<<256, 768, 0, stream>>>(in, Bt, bias, gR, gW, whh16,
                                             outp, hT, carh, carc, c, c + 1, NC, TC, 1, wOut, wHT);
      else
        fusedk<384><<<256, 768, 0, stream>>>(in, Bt, bias, gR, gW, whh16,
                                             outp, hT, carh, carc, c, c + 1, NC, TC, 1, wOut, wHT);
    }
  }

  fck<<<4, 64, 0, stream>>>(hT, fcw, fcb, out);
}